// Round 18
// baseline (145.986 us; speedup 1.0000x reference)
//
#include <hip/hip_runtime.h>

#define NFEAT 128
#define NHID  64
#define NOUT  21
#define BSH   7            // 128 nodes / bucket
#define BCAP  8192         // max edges LDS-sorted per bucket
#define CHUNK 4096         // edges per sort block (16 KB private region)
#define EPT   16           // edges per thread in k_lsort
#define PADI  16           // ints per padded counter (64 B)
#define NBUKMAX 1024       // nbuk ceiling for the packed path (N <= 2^17)

typedef unsigned int uint;
typedef unsigned short ushort_t;

typedef __bf16 bf16_t;
typedef bf16_t bf16x8 __attribute__((ext_vector_type(8)));
typedef float  f32x4  __attribute__((ext_vector_type(4)));

// bf16 pack/unpack (RTN-even)
__device__ inline uint packbf2(float a, float b) {
    uint ua = __float_as_uint(a), ub = __float_as_uint(b);
    ua = (ua + 0x7FFFu + ((ua >> 16) & 1u)) >> 16;
    ub = (ub + 0x7FFFu + ((ub >> 16) & 1u)) >> 16;
    return ua | (ub << 16);
}
__device__ inline float bflo(uint v) { return __uint_as_float(v << 16); }
__device__ inline float bfhi(uint v) { return __uint_as_float(v & 0xffff0000u); }

// ============ zero scratch ============

__global__ __launch_bounds__(256) void k_zero(uint* __restrict__ p, int n4) {
    int i = blockIdx.x * 256 + threadIdx.x;
    if (i < n4) ((uint4*)p)[i] = make_uint4(0u, 0u, 0u, 0u);
}

// ============ pass A: per-chunk LDS counting sort by bucket ============

__global__ __launch_bounds__(256) void k_lsort(const int* __restrict__ src, const int* __restrict__ dst,
                                               uint* __restrict__ ebuf, int* __restrict__ tab,
                                               int* __restrict__ gcnt, int E, int nbuk) {
    __shared__ int  lcnt[NBUKMAX + 1];
    __shared__ int  lsum[256];
    __shared__ uint lsorted[CHUNK];
    int c = blockIdx.x, tid = threadIdx.x;
    int base = c * CHUNK;
    int ccnt = min(CHUNK, E - base);

    for (int j = tid; j <= nbuk; j += 256) lcnt[j] = 0;
    __syncthreads();

    int  buk[EPT];
    uint rec[EPT];
#pragma unroll
    for (int g = 0; g < EPT / 4; ++g) {
        int e0 = base + g * 1024 + tid * 4;
        int4 dv, sv;
        if (e0 + 3 < E) {
            dv = *(const int4*)&dst[e0];
            sv = *(const int4*)&src[e0];
        } else {
            dv = make_int4(0, 0, 0, 0); sv = dv;
            if (e0     < E) { dv.x = dst[e0];     sv.x = src[e0]; }
            if (e0 + 1 < E) { dv.y = dst[e0 + 1]; sv.y = src[e0 + 1]; }
            if (e0 + 2 < E) { dv.z = dst[e0 + 2]; sv.z = src[e0 + 2]; }
        }
        int dd[4] = {dv.x, dv.y, dv.z, dv.w};
        int ss[4] = {sv.x, sv.y, sv.z, sv.w};
#pragma unroll
        for (int j = 0; j < 4; ++j) {
            int k = g * 4 + j;
            buk[k] = -1;
            if (e0 + j < E) {
                buk[k] = dd[j] >> BSH;
                rec[k] = ((uint)(dd[j] & ((1 << BSH) - 1)) << 17) | (uint)ss[j];
                atomicAdd(&lcnt[buk[k]], 1);
            }
        }
    }
    __syncthreads();

    int g = (nbuk + 255) / 256;
    int j0 = tid * g;
    int s = 0;
    for (int j = 0; j < g; ++j) { int idx = j0 + j; if (idx < nbuk) s += lcnt[idx]; }
    lsum[tid] = s;
    __syncthreads();
    for (int off = 1; off < 256; off <<= 1) {
        int t = (tid >= off) ? lsum[tid - off] : 0;
        __syncthreads();
        lsum[tid] += t;
        __syncthreads();
    }
    int run = lsum[tid] - s;
    for (int j = 0; j < g; ++j) {
        int idx = j0 + j;
        if (idx < nbuk) { int cv = lcnt[idx]; lcnt[idx] = run; run += cv; }
    }
    __syncthreads();
    if (tid == 0) lcnt[nbuk] = ccnt;
    __syncthreads();

    for (int j = tid; j < nbuk; j += 256) {
        int st = lcnt[j];
        tab[(size_t)c * (nbuk + 1) + j] = st;
        int cj = lcnt[j + 1] - st;
        if (cj) atomicAdd(&gcnt[j * PADI], cj);
    }
    if (tid == 0) tab[(size_t)c * (nbuk + 1) + nbuk] = ccnt;
    __syncthreads();

#pragma unroll
    for (int k = 0; k < EPT; ++k) {
        if (buk[k] >= 0) {
            int pos = atomicAdd(&lcnt[buk[k]], 1);
            lsorted[pos] = rec[k];
        }
    }
    __syncthreads();
    for (int i = tid * 4; i + 3 < ccnt; i += 1024)
        *(uint4*)&ebuf[base + i] = *(uint4*)&lsorted[i];
    int tail = ccnt & ~3;
    for (int i = tail + tid; i < ccnt; i += 256) ebuf[base + i] = lsorted[i];
}

// ============ pass B: single-ebuf-pass bucket sort (bscan fused) ============

__global__ __launch_bounds__(256) void k_bsort2(const uint* __restrict__ ebuf, const int* __restrict__ tab,
                                                const int* __restrict__ gcnt,
                                                int* __restrict__ rowptr, float* __restrict__ dinv,
                                                int* __restrict__ esrc, int nchunk, int nbuk, int N, int E) {
    __shared__ int  ncnt[128];
    __shared__ int  sc[128];
    __shared__ int  lcur[128];
    __shared__ int  rsum[256];
    __shared__ uint stash[BCAP];
    __shared__ int  lpos;
    int b = blockIdx.x, tid = threadIdx.x;
    int nb0 = b << BSH;
    int cnt_b = gcnt[b * PADI];
    bool fits = (cnt_b <= BCAP);

    int ps = 0;
    for (int j = tid; j < b; j += 256) ps += gcnt[j * PADI];
    rsum[tid] = ps;
    __syncthreads();
    for (int off = 128; off >= 1; off >>= 1) {
        if (tid < off) rsum[tid] += rsum[tid + off];
        __syncthreads();
    }
    int bb = rsum[0];

    if (tid < 128) ncnt[tid] = 0;
    if (tid == 0) {
        lpos = 0;
        if (b == nbuk - 1) rowptr[N] = E;
    }
    __syncthreads();

    for (int c = tid; c < nchunk; c += 256) {
        const int* trow = tab + (size_t)c * (nbuk + 1);
        int s0 = trow[b], e0 = trow[b + 1];
        int len = e0 - s0;
        if (len <= 0) continue;
        const uint* pb = ebuf + (size_t)c * CHUNK;
        if (fits) {
            int pos = atomicAdd(&lpos, len);
            for (int i = 0; i < len; ++i) {
                uint r = pb[s0 + i];
                stash[pos + i] = r;
                atomicAdd(&ncnt[r >> 17], 1);
            }
        } else {
            for (int i = 0; i < len; ++i) atomicAdd(&ncnt[pb[s0 + i] >> 17], 1);
        }
    }
    __syncthreads();

    int v = (tid < 128) ? ncnt[tid] : 0;
    if (tid < 128) sc[tid] = v;
    __syncthreads();
    for (int off = 1; off < 128; off <<= 1) {
        int t = (tid >= off && tid < 128) ? sc[tid - off] : 0;
        __syncthreads();
        if (tid < 128) sc[tid] += t;
        __syncthreads();
    }
    if (tid < 128) {
        int excl = sc[tid] - v;
        int node = nb0 + tid;
        if (node < N) {
            rowptr[node] = bb + excl;
            dinv[node] = rsqrtf((float)(v + 1));
        }
        lcur[tid] = bb + excl;
    }
    __syncthreads();

    if (fits) {
        for (int i = tid; i < cnt_b; i += 256) {
            uint r = stash[i];
            int pos = atomicAdd(&lcur[r >> 17], 1);
            esrc[pos] = (int)(r & 0x1FFFFu);
        }
    } else {
        for (int c = tid; c < nchunk; c += 256) {
            const int* trow = tab + (size_t)c * (nbuk + 1);
            int s0 = trow[b], e0 = trow[b + 1];
            const uint* pb = ebuf + (size_t)c * CHUNK;
            for (int i = s0; i < e0; ++i) {
                uint r = pb[i];
                int pos = atomicAdd(&lcur[r >> 17], 1);
                esrc[pos] = (int)(r & 0x1FFFFu);
            }
        }
    }
}

// ============ general-N fallback (N > 2^17) ============

__global__ __launch_bounds__(256) void k_count(const int* __restrict__ dst, int* cnt, int E) {
    int e = blockIdx.x * 256 + threadIdx.x;
    if (e < E) atomicAdd(&cnt[dst[e]], 1);
}

__global__ __launch_bounds__(256) void k_scan1(const int* __restrict__ cnt, int* __restrict__ rowptr,
                                               int* __restrict__ bsum, float* __restrict__ dinv, int N) {
    __shared__ int sh[256];
    int tid = threadIdx.x;
    int base = blockIdx.x * 1024 + tid * 4;
    int v[4]; int s = 0;
#pragma unroll
    for (int j = 0; j < 4; ++j) {
        v[j] = (base + j < N) ? cnt[base + j] : 0;
        if (base + j < N) dinv[base + j] = rsqrtf((float)(v[j] + 1));
        s += v[j];
    }
    sh[tid] = s; __syncthreads();
    for (int off = 1; off < 256; off <<= 1) {
        int t = (tid >= off) ? sh[tid - off] : 0;
        __syncthreads();
        sh[tid] += t;
        __syncthreads();
    }
    int run = sh[tid] - s;
#pragma unroll
    for (int j = 0; j < 4; ++j) { if (base + j < N) rowptr[base + j] = run; run += v[j]; }
    if (tid == 255) bsum[blockIdx.x] = sh[255];
}

__global__ __launch_bounds__(128) void k_scan2(int* bsum, int nb) {
    __shared__ int sh[128];
    int tid = threadIdx.x;
    int v = (tid < nb) ? bsum[tid] : 0;
    sh[tid] = v; __syncthreads();
    for (int off = 1; off < 128; off <<= 1) {
        int t = (tid >= off) ? sh[tid - off] : 0;
        __syncthreads();
        sh[tid] += t;
        __syncthreads();
    }
    if (tid < nb) bsum[tid] = sh[tid] - v;
}

__global__ __launch_bounds__(256) void k_scan3(int* __restrict__ rowptr, int* __restrict__ fill,
                                               const int* __restrict__ bsum, int N, int E) {
    int tid = threadIdx.x;
    int base = blockIdx.x * 1024 + tid * 4;
    int add = bsum[blockIdx.x];
#pragma unroll
    for (int j = 0; j < 4; ++j) {
        int idx = base + j;
        if (idx < N) {
            int r = rowptr[idx] + add;
            rowptr[idx] = r;
            fill[idx] = r;
        }
    }
    if (blockIdx.x == 0 && tid == 0) rowptr[N] = E;
}

__global__ __launch_bounds__(256) void k_scatter_direct(const int* __restrict__ src, const int* __restrict__ dst,
                                                        int* __restrict__ fill, int* __restrict__ esrc, int E) {
    int e = blockIdx.x * 256 + threadIdx.x;
    if (e >= E) return;
    int pos = atomicAdd(&fill[dst[e]], 1);
    esrc[pos] = src[e];
}

// ===== GEMM1 via MFMA: h' = dinv * (x @ W1) =====

__global__ __launch_bounds__(256) void k_gemm1(const float* __restrict__ x, const float* __restrict__ W1,
                                               const float* __restrict__ dinv, uint* __restrict__ hb, int N) {
    __shared__ ushort_t ws[64 * 136];   // W1^T bf16 [col][k], 17.4 KB
    int tid = threadIdx.x;
    int r0 = blockIdx.x * 64;

    {
        int col = tid & 63;
        int kb = (tid >> 6) * 32;
#pragma unroll
        for (int kk = 0; kk < 32; kk += 2) {
            float a = W1[(size_t)(kb + kk) * NHID + col];
            float b = W1[(size_t)(kb + kk + 1) * NHID + col];
            *(uint*)&ws[col * 136 + kb + kk] = packbf2(a, b);
        }
    }
    __syncthreads();

    int lane = tid & 63;
    int wrow = (tid >> 6) * 16;
    int lrow = lane & 15;
    int lk8  = (lane >> 4) * 8;

    int arow = r0 + wrow + lrow;
    bool aok = arow < N;
    const float* xr = x + (size_t)arow * NFEAT;

    f32x4 acc[4];
#pragma unroll
    for (int nt = 0; nt < 4; ++nt) acc[nt] = (f32x4){0.f, 0.f, 0.f, 0.f};

#pragma unroll
    for (int kq = 0; kq < 4; ++kq) {
        int kf = kq * 32 + lk8;
        float4 va = make_float4(0.f, 0.f, 0.f, 0.f), vb = va;
        if (aok) { va = *(const float4*)&xr[kf]; vb = *(const float4*)&xr[kf + 4]; }
        uint4 au = make_uint4(packbf2(va.x, va.y), packbf2(va.z, va.w),
                              packbf2(vb.x, vb.y), packbf2(vb.z, vb.w));
        bf16x8 a = *(bf16x8*)&au;
#pragma unroll
        for (int nt = 0; nt < 4; ++nt) {
            bf16x8 b = *(const bf16x8*)&ws[(nt * 16 + lrow) * 136 + kq * 32 + lk8];
            acc[nt] = __builtin_amdgcn_mfma_f32_16x16x32_bf16(a, b, acc[nt], 0, 0, 0);
        }
    }

    int orow0 = (lane >> 4) * 4;
    float dvv[4];
#pragma unroll
    for (int r = 0; r < 4; ++r) {
        int grow = r0 + wrow + orow0 + r;
        dvv[r] = (grow < N) ? dinv[grow] : 0.f;
    }
    ushort_t* hbs = (ushort_t*)hb;
#pragma unroll
    for (int nt = 0; nt < 4; ++nt) {
#pragma unroll
        for (int r = 0; r < 4; ++r) {
            int grow = r0 + wrow + orow0 + r;
            if (grow < N) {
                uint pb = packbf2(acc[nt][r] * dvv[r], 0.f);
                hbs[(size_t)grow * 64 + nt * 16 + lrow] = (ushort_t)(pb & 0xffffu);
            }
        }
    }
}

// ===== agg1: o1 = relu(b1 + dv*(h'[d] + sum_e h'[src_e])), packed bf16 out =====
// EIGHTH-wave per node: 8 lanes x uint4 = full 128 B row; 8 nodes/wave.
// 8 independent edge streams per wave; unroll 8 -> up to 64 gathers in flight.

__global__ __launch_bounds__(256) void k_agg1(const int* __restrict__ rowptr, const int* __restrict__ esrc,
                                              const uint* __restrict__ hb, const float* __restrict__ dinv,
                                              const float* __restrict__ b1, uint* __restrict__ o1b, int N) {
    int tid = threadIdx.x;
    int node = blockIdx.x * 32 + (tid >> 3);
    if (node >= N) return;
    int c = tid & 7;                           // owns feats 8c..8c+7 (one uint4)
    const uint4* hb4 = (const uint4*)hb;       // row = 8 uint4
    uint4 sv = hb4[(size_t)node * 8 + c];
    float a0 = bflo(sv.x), a1 = bfhi(sv.x), a2 = bflo(sv.y), a3 = bfhi(sv.y);
    float a4 = bflo(sv.z), a5 = bfhi(sv.z), a6 = bflo(sv.w), a7 = bfhi(sv.w);
    int beg = rowptr[node], end = rowptr[node + 1];
    int i = beg;
    for (; i + 7 < end; i += 8) {
        int s0 = esrc[i],     s1 = esrc[i + 1], s2 = esrc[i + 2], s3 = esrc[i + 3];
        int s4 = esrc[i + 4], s5 = esrc[i + 5], s6 = esrc[i + 6], s7 = esrc[i + 7];
        uint4 v0 = hb4[(size_t)s0 * 8 + c];
        uint4 v1 = hb4[(size_t)s1 * 8 + c];
        uint4 v2 = hb4[(size_t)s2 * 8 + c];
        uint4 v3 = hb4[(size_t)s3 * 8 + c];
        uint4 v4 = hb4[(size_t)s4 * 8 + c];
        uint4 v5 = hb4[(size_t)s5 * 8 + c];
        uint4 v6 = hb4[(size_t)s6 * 8 + c];
        uint4 v7 = hb4[(size_t)s7 * 8 + c];
        a0 += bflo(v0.x) + bflo(v1.x); a1 += bfhi(v0.x) + bfhi(v1.x);
        a2 += bflo(v0.y) + bflo(v1.y); a3 += bfhi(v0.y) + bfhi(v1.y);
        a4 += bflo(v0.z) + bflo(v1.z); a5 += bfhi(v0.z) + bfhi(v1.z);
        a6 += bflo(v0.w) + bflo(v1.w); a7 += bfhi(v0.w) + bfhi(v1.w);
        a0 += bflo(v2.x) + bflo(v3.x); a1 += bfhi(v2.x) + bfhi(v3.x);
        a2 += bflo(v2.y) + bflo(v3.y); a3 += bfhi(v2.y) + bfhi(v3.y);
        a4 += bflo(v2.z) + bflo(v3.z); a5 += bfhi(v2.z) + bfhi(v3.z);
        a6 += bflo(v2.w) + bflo(v3.w); a7 += bfhi(v2.w) + bfhi(v3.w);
        a0 += bflo(v4.x) + bflo(v5.x); a1 += bfhi(v4.x) + bfhi(v5.x);
        a2 += bflo(v4.y) + bflo(v5.y); a3 += bfhi(v4.y) + bfhi(v5.y);
        a4 += bflo(v4.z) + bflo(v5.z); a5 += bfhi(v4.z) + bfhi(v5.z);
        a6 += bflo(v4.w) + bflo(v5.w); a7 += bfhi(v4.w) + bfhi(v5.w);
        a0 += bflo(v6.x) + bflo(v7.x); a1 += bfhi(v6.x) + bfhi(v7.x);
        a2 += bflo(v6.y) + bflo(v7.y); a3 += bfhi(v6.y) + bfhi(v7.y);
        a4 += bflo(v6.z) + bflo(v7.z); a5 += bfhi(v6.z) + bfhi(v7.z);
        a6 += bflo(v6.w) + bflo(v7.w); a7 += bfhi(v6.w) + bfhi(v7.w);
    }
    for (; i < end; ++i) {
        uint4 v = hb4[(size_t)esrc[i] * 8 + c];
        a0 += bflo(v.x); a1 += bfhi(v.x);
        a2 += bflo(v.y); a3 += bfhi(v.y);
        a4 += bflo(v.z); a5 += bfhi(v.z);
        a6 += bflo(v.w); a7 += bfhi(v.w);
    }
    float dv = dinv[node];
    float4 bv0 = *(const float4*)&b1[c * 8];
    float4 bv1 = *(const float4*)&b1[c * 8 + 4];
    float r0 = fmaxf(fmaf(a0, dv, bv0.x), 0.f);
    float r1 = fmaxf(fmaf(a1, dv, bv0.y), 0.f);
    float r2 = fmaxf(fmaf(a2, dv, bv0.z), 0.f);
    float r3 = fmaxf(fmaf(a3, dv, bv0.w), 0.f);
    float r4 = fmaxf(fmaf(a4, dv, bv1.x), 0.f);
    float r5 = fmaxf(fmaf(a5, dv, bv1.y), 0.f);
    float r6 = fmaxf(fmaf(a6, dv, bv1.z), 0.f);
    float r7 = fmaxf(fmaf(a7, dv, bv1.w), 0.f);
    ((uint4*)o1b)[(size_t)node * 8 + c] =
        make_uint4(packbf2(r0, r1), packbf2(r2, r3), packbf2(r4, r5), packbf2(r6, r7));
}

// ===== GEMM2 via MFMA: h2' = dinv * (o1 @ W2), cols padded to 32 =====

__global__ __launch_bounds__(256) void k_gemm2m(const uint* __restrict__ o1b, const float* __restrict__ W2,
                                                const float* __restrict__ dinv, uint* __restrict__ h2b, int N) {
    __shared__ ushort_t ws[32 * 136];   // 8.7 KB
    int tid = threadIdx.x;
    int r0 = blockIdx.x * 64;

    {
        int col = tid & 31;
        int kb = (tid >> 5) * 8;
#pragma unroll
        for (int kk = 0; kk < 8; kk += 2) {
            float a = (col < NOUT) ? W2[(size_t)(kb + kk) * NOUT + col] : 0.f;
            float b = (col < NOUT) ? W2[(size_t)(kb + kk + 1) * NOUT + col] : 0.f;
            *(uint*)&ws[col * 136 + kb + kk] = packbf2(a, b);
        }
    }
    __syncthreads();

    int lane = tid & 63;
    int wrow = (tid >> 6) * 16;
    int lrow = lane & 15;
    int lk8  = (lane >> 4) * 8;

    int arow = r0 + wrow + lrow;
    bool aok = arow < N;
    const ushort_t* orp = (const ushort_t*)o1b + (size_t)arow * 64;

    f32x4 acc[2];
#pragma unroll
    for (int nt = 0; nt < 2; ++nt) acc[nt] = (f32x4){0.f, 0.f, 0.f, 0.f};

#pragma unroll
    for (int kq = 0; kq < 2; ++kq) {
        uint4 au = make_uint4(0u, 0u, 0u, 0u);
        if (aok) au = *(const uint4*)&orp[kq * 32 + lk8];
        bf16x8 a = *(bf16x8*)&au;
#pragma unroll
        for (int nt = 0; nt < 2; ++nt) {
            bf16x8 b = *(const bf16x8*)&ws[(nt * 16 + lrow) * 136 + kq * 32 + lk8];
            acc[nt] = __builtin_amdgcn_mfma_f32_16x16x32_bf16(a, b, acc[nt], 0, 0, 0);
        }
    }

    int orow0 = (lane >> 4) * 4;
    float dvv[4];
#pragma unroll
    for (int r = 0; r < 4; ++r) {
        int grow = r0 + wrow + orow0 + r;
        dvv[r] = (grow < N) ? dinv[grow] : 0.f;
    }
    ushort_t* h2s = (ushort_t*)h2b;
#pragma unroll
    for (int nt = 0; nt < 2; ++nt) {
#pragma unroll
        for (int r = 0; r < 4; ++r) {
            int grow = r0 + wrow + orow0 + r;
            if (grow < N) {
                uint pb = packbf2(acc[nt][r] * dvv[r], 0.f);
                h2s[(size_t)grow * 32 + nt * 16 + lrow] = (ushort_t)(pb & 0xffffu);
            }
        }
    }
}

// ===== agg2: out[d] = b2 + dv_d*(h2'[d] + sum_e h2'[src_e]), 8x unroll =====

__global__ __launch_bounds__(256) void k_agg2(const int* __restrict__ rowptr, const int* __restrict__ esrc,
                                              const uint* __restrict__ h2b, const float* __restrict__ dinv,
                                              const float* __restrict__ b2, float* __restrict__ out, int N) {
    int tid = threadIdx.x;
    int node = blockIdx.x * 64 + (tid >> 2);
    if (node >= N) return;
    int q = tid & 3;
    uint4 sv = *((const uint4*)(h2b + (size_t)node * 16) + q);
    float a0 = bflo(sv.x), a1 = bfhi(sv.x), a2 = bflo(sv.y), a3 = bfhi(sv.y);
    float a4 = bflo(sv.z), a5 = bfhi(sv.z), a6 = bflo(sv.w), a7 = bfhi(sv.w);
    int beg = rowptr[node], end = rowptr[node + 1];
    int i = beg;
    for (; i + 7 < end; i += 8) {
        int s0 = esrc[i],     s1 = esrc[i + 1], s2 = esrc[i + 2], s3 = esrc[i + 3];
        int s4 = esrc[i + 4], s5 = esrc[i + 5], s6 = esrc[i + 6], s7 = esrc[i + 7];
        uint4 v0 = *((const uint4*)(h2b + (size_t)s0 * 16) + q);
        uint4 v1 = *((const uint4*)(h2b + (size_t)s1 * 16) + q);
        uint4 v2 = *((const uint4*)(h2b + (size_t)s2 * 16) + q);
        uint4 v3 = *((const uint4*)(h2b + (size_t)s3 * 16) + q);
        uint4 v4 = *((const uint4*)(h2b + (size_t)s4 * 16) + q);
        uint4 v5 = *((const uint4*)(h2b + (size_t)s5 * 16) + q);
        uint4 v6 = *((const uint4*)(h2b + (size_t)s6 * 16) + q);
        uint4 v7 = *((const uint4*)(h2b + (size_t)s7 * 16) + q);
        a0 += bflo(v0.x) + bflo(v1.x); a1 += bfhi(v0.x) + bfhi(v1.x);
        a2 += bflo(v0.y) + bflo(v1.y); a3 += bfhi(v0.y) + bfhi(v1.y);
        a4 += bflo(v0.z) + bflo(v1.z); a5 += bfhi(v0.z) + bfhi(v1.z);
        a6 += bflo(v0.w) + bflo(v1.w); a7 += bfhi(v0.w) + bfhi(v1.w);
        a0 += bflo(v2.x) + bflo(v3.x); a1 += bfhi(v2.x) + bfhi(v3.x);
        a2 += bflo(v2.y) + bflo(v3.y); a3 += bfhi(v2.y) + bfhi(v3.y);
        a4 += bflo(v2.z) + bflo(v3.z); a5 += bfhi(v2.z) + bfhi(v3.z);
        a6 += bflo(v2.w) + bflo(v3.w); a7 += bfhi(v2.w) + bfhi(v3.w);
        a0 += bflo(v4.x) + bflo(v5.x); a1 += bfhi(v4.x) + bfhi(v5.x);
        a2 += bflo(v4.y) + bflo(v5.y); a3 += bfhi(v4.y) + bfhi(v5.y);
        a4 += bflo(v4.z) + bflo(v5.z); a5 += bfhi(v4.z) + bfhi(v5.z);
        a6 += bflo(v4.w) + bflo(v5.w); a7 += bfhi(v4.w) + bfhi(v5.w);
        a0 += bflo(v6.x) + bflo(v7.x); a1 += bfhi(v6.x) + bfhi(v7.x);
        a2 += bflo(v6.y) + bflo(v7.y); a3 += bfhi(v6.y) + bfhi(v7.y);
        a4 += bflo(v6.z) + bflo(v7.z); a5 += bfhi(v6.z) + bfhi(v7.z);
        a6 += bflo(v6.w) + bflo(v7.w); a7 += bfhi(v6.w) + bfhi(v7.w);
    }
    for (; i < end; ++i) {
        uint4 v0 = *((const uint4*)(h2b + (size_t)esrc[i] * 16) + q);
        a0 += bflo(v0.x); a1 += bfhi(v0.x);
        a2 += bflo(v0.y); a3 += bfhi(v0.y);
        a4 += bflo(v0.z); a5 += bfhi(v0.z);
        a6 += bflo(v0.w); a7 += bfhi(v0.w);
    }
    float dv = dinv[node];
    float* orow = out + (size_t)node * NOUT;
    int col = q * 8;
    float av[8] = {a0, a1, a2, a3, a4, a5, a6, a7};
#pragma unroll
    for (int j = 0; j < 8; ++j)
        if (col + j < NOUT) orow[col + j] = fmaf(dv, av[j], b2[col + j]);
}

// ================= launch =================

extern "C" void kernel_launch(void* const* d_in, const int* in_sizes, int n_in,
                              void* d_out, int out_size, void* d_ws, size_t ws_size,
                              hipStream_t stream) {
    const float* x  = (const float*)d_in[0];
    const int*   ei = (const int*)d_in[1];
    const float* W1 = (const float*)d_in[2];
    const float* b1 = (const float*)d_in[3];
    const float* W2 = (const float*)d_in[4];
    const float* b2 = (const float*)d_in[5];
    float* out = (float*)d_out;

    int N = in_sizes[0] / NFEAT;
    int E = in_sizes[1] / 2;
    const int* src = ei;
    const int* dst = ei + E;
    int NBUK = (N + (1 << BSH) - 1) >> BSH;
    int NCHUNK = (E + CHUNK - 1) / CHUNK;

    char* p = (char*)d_ws;
    auto alloc = [&](size_t bytes) { void* r = (void*)p; p += (bytes + 255) & ~(size_t)255; return r; };
    int*   rowptr = (int*)alloc((size_t)(N + 1) * 4);
    int*   gcnt   = (int*)alloc((size_t)NBUK * PADI * 4);
    int*   tab    = (int*)alloc((size_t)NCHUNK * (NBUK + 1) * 4);
    uint*  ebuf   = (uint*)alloc((size_t)E * 4);
    int*   esrc   = (int*)alloc((size_t)E * 4);
    float* dinv   = (float*)alloc((size_t)N * 4);
    uint*  hb     = (uint*)alloc((size_t)N * 32 * 4);   // h'  bf16 [N][64]
    uint*  o1b    = (uint*)alloc((size_t)N * 32 * 4);   // o1  bf16 [N][64]
    uint*  h2b    = (uint*)alloc((size_t)N * 16 * 4);   // h2' bf16 [N][32] (padded)
    int*   cnt    = (int*)alloc((size_t)N * 4);      // fallback only
    int*   fill   = (int*)alloc((size_t)N * 4);      // fallback only
    int*   bsum   = (int*)alloc(128 * 4);            // fallback only

    const int B = 256;

    if (N <= (1 << 17)) {
        int zn4 = (NBUK * PADI) / 4;
        k_zero  <<<(zn4 + B - 1) / B, B, 0, stream>>>((uint*)gcnt, zn4);
        k_lsort <<<NCHUNK, 256, 0, stream>>>(src, dst, ebuf, tab, gcnt, E, NBUK);
        k_bsort2<<<NBUK, 256, 0, stream>>>(ebuf, tab, gcnt, rowptr, dinv, esrc, NCHUNK, NBUK, N, E);
    } else {
        int nb = (N + 1023) / 1024;
        int zn4 = (int)(((size_t)N * 4 + 15) / 16);
        k_zero  <<<(zn4 + B - 1) / B, B, 0, stream>>>((uint*)cnt, zn4);
        k_count <<<(E + B - 1) / B, B, 0, stream>>>(dst, cnt, E);
        k_scan1 <<<nb, 256, 0, stream>>>(cnt, rowptr, bsum, dinv, N);
        k_scan2 <<<1, 128, 0, stream>>>(bsum, nb);
        k_scan3 <<<nb, 256, 0, stream>>>(rowptr, fill, bsum, N, E);
        k_scatter_direct<<<(E + B - 1) / B, B, 0, stream>>>(src, dst, fill, esrc, E);
    }

    k_gemm1 <<<(N + 63) / 64, 256, 0, stream>>>(x, W1, dinv, hb, N);
    k_agg1  <<<(N + 31) / 32, 256, 0, stream>>>(rowptr, esrc, hb, dinv, b1, o1b, N);
    k_gemm2m<<<(N + 63) / 64, 256, 0, stream>>>(o1b, W2, dinv, h2b, N);
    k_agg2  <<<(N + 63) / 64, 256, 0, stream>>>(rowptr, esrc, h2b, dinv, b2, out, N);
}

// Round 19
// 142.256 us; speedup vs baseline: 1.0262x; 1.0262x over previous
//
#include <hip/hip_runtime.h>

#define NFEAT 128
#define NHID  64
#define NOUT  21
#define BSH   7            // 128 nodes / bucket
#define BCAP  8192         // max edges LDS-sorted per bucket
#define CHUNK 4096         // edges per sort block (16 KB private region)
#define EPT   16           // edges per thread in k_lsort
#define PADI  16           // ints per padded counter (64 B)
#define NBUKMAX 1024       // nbuk ceiling for the packed path (N <= 2^17)

typedef unsigned int uint;
typedef unsigned short ushort_t;

typedef __bf16 bf16_t;
typedef bf16_t bf16x8 __attribute__((ext_vector_type(8)));
typedef float  f32x4  __attribute__((ext_vector_type(4)));

// bf16 pack/unpack (RTN-even)
__device__ inline uint packbf2(float a, float b) {
    uint ua = __float_as_uint(a), ub = __float_as_uint(b);
    ua = (ua + 0x7FFFu + ((ua >> 16) & 1u)) >> 16;
    ub = (ub + 0x7FFFu + ((ub >> 16) & 1u)) >> 16;
    return ua | (ub << 16);
}
__device__ inline float bflo(uint v) { return __uint_as_float(v << 16); }
__device__ inline float bfhi(uint v) { return __uint_as_float(v & 0xffff0000u); }

// ============ zero scratch ============

__global__ __launch_bounds__(256) void k_zero(uint* __restrict__ p, int n4) {
    int i = blockIdx.x * 256 + threadIdx.x;
    if (i < n4) ((uint4*)p)[i] = make_uint4(0u, 0u, 0u, 0u);
}

// ============ pass A: per-chunk LDS counting sort by bucket ============

__global__ __launch_bounds__(256) void k_lsort(const int* __restrict__ src, const int* __restrict__ dst,
                                               uint* __restrict__ ebuf, int* __restrict__ tab,
                                               int* __restrict__ gcnt, int E, int nbuk) {
    __shared__ int  lcnt[NBUKMAX + 1];
    __shared__ int  lsum[256];
    __shared__ uint lsorted[CHUNK];
    int c = blockIdx.x, tid = threadIdx.x;
    int base = c * CHUNK;
    int ccnt = min(CHUNK, E - base);

    for (int j = tid; j <= nbuk; j += 256) lcnt[j] = 0;
    __syncthreads();

    int  buk[EPT];
    uint rec[EPT];
#pragma unroll
    for (int g = 0; g < EPT / 4; ++g) {
        int e0 = base + g * 1024 + tid * 4;
        int4 dv, sv;
        if (e0 + 3 < E) {
            dv = *(const int4*)&dst[e0];
            sv = *(const int4*)&src[e0];
        } else {
            dv = make_int4(0, 0, 0, 0); sv = dv;
            if (e0     < E) { dv.x = dst[e0];     sv.x = src[e0]; }
            if (e0 + 1 < E) { dv.y = dst[e0 + 1]; sv.y = src[e0 + 1]; }
            if (e0 + 2 < E) { dv.z = dst[e0 + 2]; sv.z = src[e0 + 2]; }
        }
        int dd[4] = {dv.x, dv.y, dv.z, dv.w};
        int ss[4] = {sv.x, sv.y, sv.z, sv.w};
#pragma unroll
        for (int j = 0; j < 4; ++j) {
            int k = g * 4 + j;
            buk[k] = -1;
            if (e0 + j < E) {
                buk[k] = dd[j] >> BSH;
                rec[k] = ((uint)(dd[j] & ((1 << BSH) - 1)) << 17) | (uint)ss[j];
                atomicAdd(&lcnt[buk[k]], 1);
            }
        }
    }
    __syncthreads();

    int g = (nbuk + 255) / 256;
    int j0 = tid * g;
    int s = 0;
    for (int j = 0; j < g; ++j) { int idx = j0 + j; if (idx < nbuk) s += lcnt[idx]; }
    lsum[tid] = s;
    __syncthreads();
    for (int off = 1; off < 256; off <<= 1) {
        int t = (tid >= off) ? lsum[tid - off] : 0;
        __syncthreads();
        lsum[tid] += t;
        __syncthreads();
    }
    int run = lsum[tid] - s;
    for (int j = 0; j < g; ++j) {
        int idx = j0 + j;
        if (idx < nbuk) { int cv = lcnt[idx]; lcnt[idx] = run; run += cv; }
    }
    __syncthreads();
    if (tid == 0) lcnt[nbuk] = ccnt;
    __syncthreads();

    for (int j = tid; j < nbuk; j += 256) {
        int st = lcnt[j];
        tab[(size_t)c * (nbuk + 1) + j] = st;
        int cj = lcnt[j + 1] - st;
        if (cj) atomicAdd(&gcnt[j * PADI], cj);
    }
    if (tid == 0) tab[(size_t)c * (nbuk + 1) + nbuk] = ccnt;
    __syncthreads();

#pragma unroll
    for (int k = 0; k < EPT; ++k) {
        if (buk[k] >= 0) {
            int pos = atomicAdd(&lcnt[buk[k]], 1);
            lsorted[pos] = rec[k];
        }
    }
    __syncthreads();
    for (int i = tid * 4; i + 3 < ccnt; i += 1024)
        *(uint4*)&ebuf[base + i] = *(uint4*)&lsorted[i];
    int tail = ccnt & ~3;
    for (int i = tail + tid; i < ccnt; i += 256) ebuf[base + i] = lsorted[i];
}

// ============ pass B: single-ebuf-pass bucket sort (bscan fused) ============

__global__ __launch_bounds__(256) void k_bsort2(const uint* __restrict__ ebuf, const int* __restrict__ tab,
                                                const int* __restrict__ gcnt,
                                                int* __restrict__ rowptr, float* __restrict__ dinv,
                                                int* __restrict__ esrc, int nchunk, int nbuk, int N, int E) {
    __shared__ int  ncnt[128];
    __shared__ int  sc[128];
    __shared__ int  lcur[128];
    __shared__ int  rsum[256];
    __shared__ uint stash[BCAP];
    __shared__ int  lpos;
    int b = blockIdx.x, tid = threadIdx.x;
    int nb0 = b << BSH;
    int cnt_b = gcnt[b * PADI];
    bool fits = (cnt_b <= BCAP);

    int ps = 0;
    for (int j = tid; j < b; j += 256) ps += gcnt[j * PADI];
    rsum[tid] = ps;
    __syncthreads();
    for (int off = 128; off >= 1; off >>= 1) {
        if (tid < off) rsum[tid] += rsum[tid + off];
        __syncthreads();
    }
    int bb = rsum[0];

    if (tid < 128) ncnt[tid] = 0;
    if (tid == 0) {
        lpos = 0;
        if (b == nbuk - 1) rowptr[N] = E;
    }
    __syncthreads();

    for (int c = tid; c < nchunk; c += 256) {
        const int* trow = tab + (size_t)c * (nbuk + 1);
        int s0 = trow[b], e0 = trow[b + 1];
        int len = e0 - s0;
        if (len <= 0) continue;
        const uint* pb = ebuf + (size_t)c * CHUNK;
        if (fits) {
            int pos = atomicAdd(&lpos, len);
            for (int i = 0; i < len; ++i) {
                uint r = pb[s0 + i];
                stash[pos + i] = r;
                atomicAdd(&ncnt[r >> 17], 1);
            }
        } else {
            for (int i = 0; i < len; ++i) atomicAdd(&ncnt[pb[s0 + i] >> 17], 1);
        }
    }
    __syncthreads();

    int v = (tid < 128) ? ncnt[tid] : 0;
    if (tid < 128) sc[tid] = v;
    __syncthreads();
    for (int off = 1; off < 128; off <<= 1) {
        int t = (tid >= off && tid < 128) ? sc[tid - off] : 0;
        __syncthreads();
        if (tid < 128) sc[tid] += t;
        __syncthreads();
    }
    if (tid < 128) {
        int excl = sc[tid] - v;
        int node = nb0 + tid;
        if (node < N) {
            rowptr[node] = bb + excl;
            dinv[node] = rsqrtf((float)(v + 1));
        }
        lcur[tid] = bb + excl;
    }
    __syncthreads();

    if (fits) {
        for (int i = tid; i < cnt_b; i += 256) {
            uint r = stash[i];
            int pos = atomicAdd(&lcur[r >> 17], 1);
            esrc[pos] = (int)(r & 0x1FFFFu);
        }
    } else {
        for (int c = tid; c < nchunk; c += 256) {
            const int* trow = tab + (size_t)c * (nbuk + 1);
            int s0 = trow[b], e0 = trow[b + 1];
            const uint* pb = ebuf + (size_t)c * CHUNK;
            for (int i = s0; i < e0; ++i) {
                uint r = pb[i];
                int pos = atomicAdd(&lcur[r >> 17], 1);
                esrc[pos] = (int)(r & 0x1FFFFu);
            }
        }
    }
}

// ============ general-N fallback (N > 2^17) ============

__global__ __launch_bounds__(256) void k_count(const int* __restrict__ dst, int* cnt, int E) {
    int e = blockIdx.x * 256 + threadIdx.x;
    if (e < E) atomicAdd(&cnt[dst[e]], 1);
}

__global__ __launch_bounds__(256) void k_scan1(const int* __restrict__ cnt, int* __restrict__ rowptr,
                                               int* __restrict__ bsum, float* __restrict__ dinv, int N) {
    __shared__ int sh[256];
    int tid = threadIdx.x;
    int base = blockIdx.x * 1024 + tid * 4;
    int v[4]; int s = 0;
#pragma unroll
    for (int j = 0; j < 4; ++j) {
        v[j] = (base + j < N) ? cnt[base + j] : 0;
        if (base + j < N) dinv[base + j] = rsqrtf((float)(v[j] + 1));
        s += v[j];
    }
    sh[tid] = s; __syncthreads();
    for (int off = 1; off < 256; off <<= 1) {
        int t = (tid >= off) ? sh[tid - off] : 0;
        __syncthreads();
        sh[tid] += t;
        __syncthreads();
    }
    int run = sh[tid] - s;
#pragma unroll
    for (int j = 0; j < 4; ++j) { if (base + j < N) rowptr[base + j] = run; run += v[j]; }
    if (tid == 255) bsum[blockIdx.x] = sh[255];
}

__global__ __launch_bounds__(128) void k_scan2(int* bsum, int nb) {
    __shared__ int sh[128];
    int tid = threadIdx.x;
    int v = (tid < nb) ? bsum[tid] : 0;
    sh[tid] = v; __syncthreads();
    for (int off = 1; off < 128; off <<= 1) {
        int t = (tid >= off) ? sh[tid - off] : 0;
        __syncthreads();
        sh[tid] += t;
        __syncthreads();
    }
    if (tid < nb) bsum[tid] = sh[tid] - v;
}

__global__ __launch_bounds__(256) void k_scan3(int* __restrict__ rowptr, int* __restrict__ fill,
                                               const int* __restrict__ bsum, int N, int E) {
    int tid = threadIdx.x;
    int base = blockIdx.x * 1024 + tid * 4;
    int add = bsum[blockIdx.x];
#pragma unroll
    for (int j = 0; j < 4; ++j) {
        int idx = base + j;
        if (idx < N) {
            int r = rowptr[idx] + add;
            rowptr[idx] = r;
            fill[idx] = r;
        }
    }
    if (blockIdx.x == 0 && tid == 0) rowptr[N] = E;
}

__global__ __launch_bounds__(256) void k_scatter_direct(const int* __restrict__ src, const int* __restrict__ dst,
                                                        int* __restrict__ fill, int* __restrict__ esrc, int E) {
    int e = blockIdx.x * 256 + threadIdx.x;
    if (e >= E) return;
    int pos = atomicAdd(&fill[dst[e]], 1);
    esrc[pos] = src[e];
}

// ===== GEMM1 via MFMA: h' = dinv * (x @ W1) =====
// A-fragments loaded directly from global x into registers; W1^T in LDS.

__global__ __launch_bounds__(256) void k_gemm1(const float* __restrict__ x, const float* __restrict__ W1,
                                               const float* __restrict__ dinv, uint* __restrict__ hb, int N) {
    __shared__ ushort_t ws[64 * 136];   // W1^T bf16 [col][k], 17.4 KB
    int tid = threadIdx.x;
    int r0 = blockIdx.x * 64;

    {
        int col = tid & 63;
        int kb = (tid >> 6) * 32;
#pragma unroll
        for (int kk = 0; kk < 32; kk += 2) {
            float a = W1[(size_t)(kb + kk) * NHID + col];
            float b = W1[(size_t)(kb + kk + 1) * NHID + col];
            *(uint*)&ws[col * 136 + kb + kk] = packbf2(a, b);
        }
    }
    __syncthreads();

    int lane = tid & 63;
    int wrow = (tid >> 6) * 16;
    int lrow = lane & 15;
    int lk8  = (lane >> 4) * 8;

    int arow = r0 + wrow + lrow;
    bool aok = arow < N;
    const float* xr = x + (size_t)arow * NFEAT;

    f32x4 acc[4];
#pragma unroll
    for (int nt = 0; nt < 4; ++nt) acc[nt] = (f32x4){0.f, 0.f, 0.f, 0.f};

#pragma unroll
    for (int kq = 0; kq < 4; ++kq) {
        int kf = kq * 32 + lk8;
        float4 va = make_float4(0.f, 0.f, 0.f, 0.f), vb = va;
        if (aok) { va = *(const float4*)&xr[kf]; vb = *(const float4*)&xr[kf + 4]; }
        uint4 au = make_uint4(packbf2(va.x, va.y), packbf2(va.z, va.w),
                              packbf2(vb.x, vb.y), packbf2(vb.z, vb.w));
        bf16x8 a = *(bf16x8*)&au;
#pragma unroll
        for (int nt = 0; nt < 4; ++nt) {
            bf16x8 b = *(const bf16x8*)&ws[(nt * 16 + lrow) * 136 + kq * 32 + lk8];
            acc[nt] = __builtin_amdgcn_mfma_f32_16x16x32_bf16(a, b, acc[nt], 0, 0, 0);
        }
    }

    int orow0 = (lane >> 4) * 4;
    float dvv[4];
#pragma unroll
    for (int r = 0; r < 4; ++r) {
        int grow = r0 + wrow + orow0 + r;
        dvv[r] = (grow < N) ? dinv[grow] : 0.f;
    }
    ushort_t* hbs = (ushort_t*)hb;
#pragma unroll
    for (int nt = 0; nt < 4; ++nt) {
#pragma unroll
        for (int r = 0; r < 4; ++r) {
            int grow = r0 + wrow + orow0 + r;
            if (grow < N) {
                uint pb = packbf2(acc[nt][r] * dvv[r], 0.f);
                hbs[(size_t)grow * 64 + nt * 16 + lrow] = (ushort_t)(pb & 0xffffu);
            }
        }
    }
}

// ===== agg1: o1 = relu(b1 + dv*(h'[d] + sum_e h'[src_e])), packed bf16 out =====
// Quarter-wave per node: 16 lanes x uint2 = full 128 B row; 4 nodes/wave.
// (Bracketed optimum: 64-lane=53us, 16-lane=38us, 8-lane=42us.)

__global__ __launch_bounds__(256) void k_agg1(const int* __restrict__ rowptr, const int* __restrict__ esrc,
                                              const uint* __restrict__ hb, const float* __restrict__ dinv,
                                              const float* __restrict__ b1, uint* __restrict__ o1b, int N) {
    int tid = threadIdx.x;
    int node = blockIdx.x * 16 + (tid >> 4);
    if (node >= N) return;
    int c = tid & 15;
    const uint2* hb2 = (const uint2*)hb;
    uint2 sv = hb2[(size_t)node * 16 + c];
    float a0 = bflo(sv.x), a1 = bfhi(sv.x), a2 = bflo(sv.y), a3 = bfhi(sv.y);
    int beg = rowptr[node], end = rowptr[node + 1];
    int i = beg;
    for (; i + 7 < end; i += 8) {
        int s0 = esrc[i],     s1 = esrc[i + 1], s2 = esrc[i + 2], s3 = esrc[i + 3];
        int s4 = esrc[i + 4], s5 = esrc[i + 5], s6 = esrc[i + 6], s7 = esrc[i + 7];
        uint2 v0 = hb2[(size_t)s0 * 16 + c];
        uint2 v1 = hb2[(size_t)s1 * 16 + c];
        uint2 v2 = hb2[(size_t)s2 * 16 + c];
        uint2 v3 = hb2[(size_t)s3 * 16 + c];
        uint2 v4 = hb2[(size_t)s4 * 16 + c];
        uint2 v5 = hb2[(size_t)s5 * 16 + c];
        uint2 v6 = hb2[(size_t)s6 * 16 + c];
        uint2 v7 = hb2[(size_t)s7 * 16 + c];
        a0 += bflo(v0.x) + bflo(v1.x); a1 += bfhi(v0.x) + bfhi(v1.x);
        a2 += bflo(v0.y) + bflo(v1.y); a3 += bfhi(v0.y) + bfhi(v1.y);
        a0 += bflo(v2.x) + bflo(v3.x); a1 += bfhi(v2.x) + bfhi(v3.x);
        a2 += bflo(v2.y) + bflo(v3.y); a3 += bfhi(v2.y) + bfhi(v3.y);
        a0 += bflo(v4.x) + bflo(v5.x); a1 += bfhi(v4.x) + bfhi(v5.x);
        a2 += bflo(v4.y) + bflo(v5.y); a3 += bfhi(v4.y) + bfhi(v5.y);
        a0 += bflo(v6.x) + bflo(v7.x); a1 += bfhi(v6.x) + bfhi(v7.x);
        a2 += bflo(v6.y) + bflo(v7.y); a3 += bfhi(v6.y) + bfhi(v7.y);
    }
    for (; i < end; ++i) {
        uint2 v = hb2[(size_t)esrc[i] * 16 + c];
        a0 += bflo(v.x); a1 += bfhi(v.x);
        a2 += bflo(v.y); a3 += bfhi(v.y);
    }
    float dv = dinv[node];
    float4 bv = *(const float4*)&b1[c * 4];
    float r0 = fmaxf(fmaf(a0, dv, bv.x), 0.f);
    float r1 = fmaxf(fmaf(a1, dv, bv.y), 0.f);
    float r2 = fmaxf(fmaf(a2, dv, bv.z), 0.f);
    float r3 = fmaxf(fmaf(a3, dv, bv.w), 0.f);
    ((uint2*)o1b)[(size_t)node * 16 + c] = make_uint2(packbf2(r0, r1), packbf2(r2, r3));
}

// ===== GEMM2 via MFMA: h2' = dinv * (o1 @ W2), cols padded to 32 =====

__global__ __launch_bounds__(256) void k_gemm2m(const uint* __restrict__ o1b, const float* __restrict__ W2,
                                                const float* __restrict__ dinv, uint* __restrict__ h2b, int N) {
    __shared__ ushort_t ws[32 * 136];   // 8.7 KB
    int tid = threadIdx.x;
    int r0 = blockIdx.x * 64;

    {
        int col = tid & 31;
        int kb = (tid >> 5) * 8;
#pragma unroll
        for (int kk = 0; kk < 8; kk += 2) {
            float a = (col < NOUT) ? W2[(size_t)(kb + kk) * NOUT + col] : 0.f;
            float b = (col < NOUT) ? W2[(size_t)(kb + kk + 1) * NOUT + col] : 0.f;
            *(uint*)&ws[col * 136 + kb + kk] = packbf2(a, b);
        }
    }
    __syncthreads();

    int lane = tid & 63;
    int wrow = (tid >> 6) * 16;
    int lrow = lane & 15;
    int lk8  = (lane >> 4) * 8;

    int arow = r0 + wrow + lrow;
    bool aok = arow < N;
    const ushort_t* orp = (const ushort_t*)o1b + (size_t)arow * 64;

    f32x4 acc[2];
#pragma unroll
    for (int nt = 0; nt < 2; ++nt) acc[nt] = (f32x4){0.f, 0.f, 0.f, 0.f};

#pragma unroll
    for (int kq = 0; kq < 2; ++kq) {
        uint4 au = make_uint4(0u, 0u, 0u, 0u);
        if (aok) au = *(const uint4*)&orp[kq * 32 + lk8];
        bf16x8 a = *(bf16x8*)&au;
#pragma unroll
        for (int nt = 0; nt < 2; ++nt) {
            bf16x8 b = *(const bf16x8*)&ws[(nt * 16 + lrow) * 136 + kq * 32 + lk8];
            acc[nt] = __builtin_amdgcn_mfma_f32_16x16x32_bf16(a, b, acc[nt], 0, 0, 0);
        }
    }

    int orow0 = (lane >> 4) * 4;
    float dvv[4];
#pragma unroll
    for (int r = 0; r < 4; ++r) {
        int grow = r0 + wrow + orow0 + r;
        dvv[r] = (grow < N) ? dinv[grow] : 0.f;
    }
    ushort_t* h2s = (ushort_t*)h2b;
#pragma unroll
    for (int nt = 0; nt < 2; ++nt) {
#pragma unroll
        for (int r = 0; r < 4; ++r) {
            int grow = r0 + wrow + orow0 + r;
            if (grow < N) {
                uint pb = packbf2(acc[nt][r] * dvv[r], 0.f);
                h2s[(size_t)grow * 32 + nt * 16 + lrow] = (ushort_t)(pb & 0xffffu);
            }
        }
    }
}

// ===== agg2: out[d] = b2 + dv_d*(h2'[d] + sum_e h2'[src_e]), 4x unroll =====

__global__ __launch_bounds__(256) void k_agg2(const int* __restrict__ rowptr, const int* __restrict__ esrc,
                                              const uint* __restrict__ h2b, const float* __restrict__ dinv,
                                              const float* __restrict__ b2, float* __restrict__ out, int N) {
    int tid = threadIdx.x;
    int node = blockIdx.x * 64 + (tid >> 2);
    if (node >= N) return;
    int q = tid & 3;
    uint4 sv = *((const uint4*)(h2b + (size_t)node * 16) + q);
    float a0 = bflo(sv.x), a1 = bfhi(sv.x), a2 = bflo(sv.y), a3 = bfhi(sv.y);
    float a4 = bflo(sv.z), a5 = bfhi(sv.z), a6 = bflo(sv.w), a7 = bfhi(sv.w);
    int beg = rowptr[node], end = rowptr[node + 1];
    int i = beg;
    for (; i + 3 < end; i += 4) {
        int s0 = esrc[i], s1 = esrc[i + 1], s2 = esrc[i + 2], s3 = esrc[i + 3];
        uint4 v0 = *((const uint4*)(h2b + (size_t)s0 * 16) + q);
        uint4 v1 = *((const uint4*)(h2b + (size_t)s1 * 16) + q);
        uint4 v2 = *((const uint4*)(h2b + (size_t)s2 * 16) + q);
        uint4 v3 = *((const uint4*)(h2b + (size_t)s3 * 16) + q);
        a0 += bflo(v0.x) + bflo(v1.x);
        a1 += bfhi(v0.x) + bfhi(v1.x);
        a2 += bflo(v0.y) + bflo(v1.y);
        a3 += bfhi(v0.y) + bfhi(v1.y);
        a4 += bflo(v0.z) + bflo(v1.z);
        a5 += bfhi(v0.z) + bfhi(v1.z);
        a6 += bflo(v0.w) + bflo(v1.w);
        a7 += bfhi(v0.w) + bfhi(v1.w);
        a0 += bflo(v2.x) + bflo(v3.x);
        a1 += bfhi(v2.x) + bfhi(v3.x);
        a2 += bflo(v2.y) + bflo(v3.y);
        a3 += bfhi(v2.y) + bfhi(v3.y);
        a4 += bflo(v2.z) + bflo(v3.z);
        a5 += bfhi(v2.z) + bfhi(v3.z);
        a6 += bflo(v2.w) + bflo(v3.w);
        a7 += bfhi(v2.w) + bfhi(v3.w);
    }
    for (; i < end; ++i) {
        uint4 v0 = *((const uint4*)(h2b + (size_t)esrc[i] * 16) + q);
        a0 += bflo(v0.x); a1 += bfhi(v0.x);
        a2 += bflo(v0.y); a3 += bfhi(v0.y);
        a4 += bflo(v0.z); a5 += bfhi(v0.z);
        a6 += bflo(v0.w); a7 += bfhi(v0.w);
    }
    float dv = dinv[node];
    float* orow = out + (size_t)node * NOUT;
    int col = q * 8;
    float av[8] = {a0, a1, a2, a3, a4, a5, a6, a7};
#pragma unroll
    for (int j = 0; j < 8; ++j)
        if (col + j < NOUT) orow[col + j] = fmaf(dv, av[j], b2[col + j]);
}

// ================= launch =================

extern "C" void kernel_launch(void* const* d_in, const int* in_sizes, int n_in,
                              void* d_out, int out_size, void* d_ws, size_t ws_size,
                              hipStream_t stream) {
    const float* x  = (const float*)d_in[0];
    const int*   ei = (const int*)d_in[1];
    const float* W1 = (const float*)d_in[2];
    const float* b1 = (const float*)d_in[3];
    const float* W2 = (const float*)d_in[4];
    const float* b2 = (const float*)d_in[5];
    float* out = (float*)d_out;

    int N = in_sizes[0] / NFEAT;
    int E = in_sizes[1] / 2;
    const int* src = ei;
    const int* dst = ei + E;
    int NBUK = (N + (1 << BSH) - 1) >> BSH;
    int NCHUNK = (E + CHUNK - 1) / CHUNK;

    char* p = (char*)d_ws;
    auto alloc = [&](size_t bytes) { void* r = (void*)p; p += (bytes + 255) & ~(size_t)255; return r; };
    int*   rowptr = (int*)alloc((size_t)(N + 1) * 4);
    int*   gcnt   = (int*)alloc((size_t)NBUK * PADI * 4);
    int*   tab    = (int*)alloc((size_t)NCHUNK * (NBUK + 1) * 4);
    uint*  ebuf   = (uint*)alloc((size_t)E * 4);
    int*   esrc   = (int*)alloc((size_t)E * 4);
    float* dinv   = (float*)alloc((size_t)N * 4);
    uint*  hb     = (uint*)alloc((size_t)N * 32 * 4);   // h'  bf16 [N][64]
    uint*  o1b    = (uint*)alloc((size_t)N * 32 * 4);   // o1  bf16 [N][64]
    uint*  h2b    = (uint*)alloc((size_t)N * 16 * 4);   // h2' bf16 [N][32] (padded)
    int*   cnt    = (int*)alloc((size_t)N * 4);      // fallback only
    int*   fill   = (int*)alloc((size_t)N * 4);      // fallback only
    int*   bsum   = (int*)alloc(128 * 4);            // fallback only

    const int B = 256;

    if (N <= (1 << 17)) {
        int zn4 = (NBUK * PADI) / 4;
        k_zero  <<<(zn4 + B - 1) / B, B, 0, stream>>>((uint*)gcnt, zn4);
        k_lsort <<<NCHUNK, 256, 0, stream>>>(src, dst, ebuf, tab, gcnt, E, NBUK);
        k_bsort2<<<NBUK, 256, 0, stream>>>(ebuf, tab, gcnt, rowptr, dinv, esrc, NCHUNK, NBUK, N, E);
    } else {
        int nb = (N + 1023) / 1024;
        int zn4 = (int)(((size_t)N * 4 + 15) / 16);
        k_zero  <<<(zn4 + B - 1) / B, B, 0, stream>>>((uint*)cnt, zn4);
        k_count <<<(E + B - 1) / B, B, 0, stream>>>(dst, cnt, E);
        k_scan1 <<<nb, 256, 0, stream>>>(cnt, rowptr, bsum, dinv, N);
        k_scan2 <<<1, 128, 0, stream>>>(bsum, nb);
        k_scan3 <<<nb, 256, 0, stream>>>(rowptr, fill, bsum, N, E);
        k_scatter_direct<<<(E + B - 1) / B, B, 0, stream>>>(src, dst, fill, esrc, E);
    }

    k_gemm1 <<<(N + 63) / 64, 256, 0, stream>>>(x, W1, dinv, hb, N);
    k_agg1  <<<(N + 15) / 16, 256, 0, stream>>>(rowptr, esrc, hb, dinv, b1, o1b, N);
    k_gemm2m<<<(N + 63) / 64, 256, 0, stream>>>(o1b, W2, dinv, h2b, N);
    k_agg2  <<<(N + 63) / 64, 256, 0, stream>>>(rowptr, esrc, h2b, dinv, b2, out, N);
}